// Round 16
// baseline (571.837 us; speedup 1.0000x reference)
//
#include <hip/hip_runtime.h>
#include <hip/hip_bf16.h>

#define CIN 1024
#define HW2 9216
#define COUT 256
#define NSH 4
#define RHID 64
#define CPG 8
#define EPSV 1e-5f
#define GRPSZ (CPG * HW2)

typedef __attribute__((ext_vector_type(8))) short bf16x8;
typedef __attribute__((ext_vector_type(4))) float f32x4;

__device__ __forceinline__ unsigned short f2bf(float f) {
  unsigned u = __builtin_bit_cast(unsigned, f);
  u = (u + 0x7fffu + ((u >> 16) & 1u)) >> 16;
  return (unsigned short)u;
}
__device__ __forceinline__ float bf2f(unsigned short h) {
  unsigned u = (unsigned)h << 16;
  return __builtin_bit_cast(float, u);
}

// ---- kernel 1: feat -> bf16 B-panels (lane-major) + GAP partial sums -------
// B-panel: p = (b*32+kq)*576 + np  (np = n>>4). Within (512 ushort):
//   lane l = (kchunk c = l>>4)*16 + (n16 = l&15) holds k=kq*32+c*8+j, col n.
//   ushort off = l*8 + j  -> GEMM fragment load is ONE dwordx4 at l*16 bytes.
__global__ __launch_bounds__(256) void k_prep(
    const float* __restrict__ feat, unsigned short* __restrict__ fbp,
    float* __restrict__ pooledpart) {
  __shared__ unsigned short T[512][36];
  const int seg = blockIdx.x, kq = blockIdx.y, b = blockIdx.z;
  const int tid = threadIdx.x;
  const int r = tid >> 3;          // k-row 0..31
  const int c8 = tid & 7;
  const float* f0 = feat + ((size_t)(b * CIN + kq * 32 + r)) * HW2 + seg * 512;
  float s = 0.f;
  #pragma unroll
  for (int p = 0; p < 16; ++p) {
    int n0 = (c8 + p * 8) * 4;
    float4 v = *(const float4*)(f0 + n0);
    s += v.x + v.y + v.z + v.w;
    T[n0][r]     = f2bf(v.x);
    T[n0 + 1][r] = f2bf(v.y);
    T[n0 + 2][r] = f2bf(v.z);
    T[n0 + 3][r] = f2bf(v.w);
  }
  s += __shfl_down(s, 4); s += __shfl_down(s, 2); s += __shfl_down(s, 1);
  if (c8 == 0)
    pooledpart[((size_t)(b * CIN + kq * 32 + r)) * 18 + seg] = s;
  __syncthreads();
  unsigned short* dbase = fbp + ((size_t)((b * 32 + kq) * 576) + seg * 32) * 512;
  #pragma unroll
  for (int i = 0; i < 8; ++i) {
    int u = i * 256 + tid;           // 2048 chunks: panel pl, lane-chunk l
    int pl = u >> 6, l = u & 63;
    int n = pl * 16 + (l & 15), c = l >> 4;
    uint2 lo = *(const uint2*)&T[n][c * 8];
    uint2 hi = *(const uint2*)&T[n][c * 8 + 4];
    uint4 o = make_uint4(lo.x, lo.y, hi.x, hi.y);
    *(uint4*)(dbase + (size_t)pl * 512 + l * 8) = o;
  }
}

// ---- kernel 1b: reduce 18 seg-partials -> pooled ---------------------------
__global__ __launch_bounds__(256) void k_red(
    const float* __restrict__ pooledpart, float* __restrict__ pooled) {
  int row = blockIdx.x * 256 + threadIdx.x;
  const float* p = pooledpart + (size_t)row * 18;
  float s = 0.f;
  #pragma unroll
  for (int i = 0; i < 18; ++i) s += p[i];
  pooled[row] = s;
}

// ---- kernel 2a: SE mlp -> s[b][4] ------------------------------------------
__global__ __launch_bounds__(256) void k_se(
    const float* __restrict__ pooled, const float* __restrict__ w1,
    const float* __restrict__ b1, const float* __restrict__ w2,
    const float* __restrict__ b2, float* __restrict__ sg) {
  int b = blockIdx.x;
  int r = threadIdx.x & 63, q = threadIdx.x >> 6;
  const float* pp = pooled + b * CIN + q * 256;
  const float* wrow = w1 + (size_t)r * CIN + q * 256;
  float acc = 0.f;
  for (int c = 0; c < 256; ++c) acc += pp[c] * wrow[c];
  __shared__ float part[4][64];
  __shared__ float hid[64];
  part[q][r] = acc;
  __syncthreads();
  if (q == 0) {
    float h = (part[0][r] + part[1][r] + part[2][r] + part[3][r]) *
                  (1.f / (float)HW2) + b1[r];
    hid[r] = h > 0.f ? h : 0.f;
  }
  __syncthreads();
  if (threadIdx.x < NSH) {
    float a = 0.f;
    for (int k = 0; k < RHID; ++k) a += hid[k] * w2[threadIdx.x * RHID + k];
    a += b2[threadIdx.x];
    sg[b * NSH + threadIdx.x] = 1.f / (1.f + expf(-a));
  }
}

// ---- kernel 2b: conv_weight -> bf16 A-panels (lane-major); zero stpart -----
// A-panel: p = (b*16+m16)*32 + kq. lane l = (c = l>>4)*16 + (r = l&15) holds
// row m16*16+r, k = kq*32+c*8+j. ushort off = l*8+j.
__global__ __launch_bounds__(256) void k_cw(
    const float* __restrict__ w_red, const float* __restrict__ sg,
    unsigned short* __restrict__ apnl, float* __restrict__ stpart) {
  if (blockIdx.x == 0) {
    stpart[threadIdx.x] = 0.f;
    stpart[256 + threadIdx.x] = 0.f;
  }
  int u = blockIdx.x * 256 + threadIdx.x;   // chunk id < 262144
  int l = u & 63, kq = (u >> 6) & 31, m16 = (u >> 11) & 15, b = u >> 15;
  int m = m16 * 16 + (l & 15), k = kq * 32 + (l >> 4) * 8;
  float sv = sg[b * NSH + (k >> 8)];
  const float* src = w_red + (size_t)m * CIN + k;
  float4 v0 = *(const float4*)(src);
  float4 v1 = *(const float4*)(src + 4);
  bf16x8 o;
  o[0] = (short)f2bf(v0.x * sv); o[1] = (short)f2bf(v0.y * sv);
  o[2] = (short)f2bf(v0.z * sv); o[3] = (short)f2bf(v0.w * sv);
  o[4] = (short)f2bf(v1.x * sv); o[5] = (short)f2bf(v1.y * sv);
  o[6] = (short)f2bf(v1.z * sv); o[7] = (short)f2bf(v1.w * sv);
  *(bf16x8*)(apnl + ((size_t)((b * 16 + m16) * 32 + kq)) * 512 + l * 8) = o;
}

// ---- kernel 3: LDS-free direct-fragment GEMM (flatmm style) ----------------
// BM=256, BN=64; 256 thr = 4 waves stacked in M (wave tile 64x64).
// No LDS, no barriers: fragments stream global->VGPR from panel buffers.
template <typename Fin>
__device__ __forceinline__ void gemm_body(
    const unsigned short* __restrict__ fbp,
    const unsigned short* __restrict__ apnl, int nt, int b, Fin&& finish) {
  const int tid = threadIdx.x, lane = tid & 63, w = tid >> 6;
  const char* ap0 = (const char*)apnl +
                    (((size_t)((b * 16 + w * 4) * 32)) << 10) + lane * 16;
  const char* bp0 = (const char*)fbp +
                    (((size_t)(b * 32) * 576 + nt * 4) << 10) + lane * 16;

  f32x4 acc[4][4] = {};
  bf16x8 aA[4], bA[4], aB[4], bB[4];

  auto LD = [&](bf16x8 (&af)[4], bf16x8 (&bf)[4], int kq) {
    #pragma unroll
    for (int mi = 0; mi < 4; ++mi)
      af[mi] = *(const bf16x8*)(ap0 + mi * 32768 + kq * 1024);
    #pragma unroll
    for (int ni = 0; ni < 4; ++ni)
      bf[ni] = *(const bf16x8*)(bp0 + (size_t)kq * 589824 + ni * 1024);
  };
  auto FM = [&](bf16x8 (&af)[4], bf16x8 (&bf)[4]) {
    #pragma unroll
    for (int mi = 0; mi < 4; ++mi)
      #pragma unroll
      for (int ni = 0; ni < 4; ++ni)
        acc[mi][ni] = __builtin_amdgcn_mfma_f32_16x16x32_bf16(
            af[mi], bf[ni], acc[mi][ni], 0, 0, 0);
  };

  LD(aA, bA, 0);
  #pragma unroll
  for (int kq = 0; kq < 30; kq += 2) {   // static 2-deep register pipeline
    LD(aB, bB, kq + 1);
    FM(aA, bA);
    LD(aA, bA, kq + 2);
    FM(aB, bB);
  }
  LD(aB, bB, 31);
  FM(aA, bA);
  FM(aB, bB);

  finish(acc, lane, w);
}

__device__ __forceinline__ void gemm_epilogue(
    f32x4 (&acc)[4][4], int lane, int w, int nt,
    unsigned short* __restrict__ ob, float* __restrict__ stp) {
  #pragma unroll
  for (int mi = 0; mi < 4; ++mi) {
    int r0 = w * 64 + mi * 16 + ((lane >> 4) << 2);
    #pragma unroll
    for (int ni = 0; ni < 4; ++ni) {
      int p = nt * 64 + ni * 16 + (lane & 15);
      #pragma unroll
      for (int j = 0; j < 4; ++j)
        ob[(size_t)(r0 + j) * HW2 + p] = f2bf(acc[mi][ni][j]);
    }
  }
  #pragma unroll
  for (int mi = 0; mi < 4; ++mi) {
    float s1 = 0.f, s2 = 0.f;
    #pragma unroll
    for (int ni = 0; ni < 4; ++ni)
      #pragma unroll
      for (int j = 0; j < 4; ++j) {
        float v = acc[mi][ni][j];
        s1 += v; s2 += v * v;
      }
    #pragma unroll
    for (int off = 1; off <= 16; off <<= 1) {
      s1 += __shfl_xor(s1, off);
      s2 += __shfl_xor(s2, off);
    }
    if ((lane & 31) == 0) {
      int g = w * 8 + mi * 2 + (lane >> 5);
      atomicAdd(&stp[g * 2], s1);
      atomicAdd(&stp[g * 2 + 1], s2);
    }
  }
}

__global__ __launch_bounds__(256, 3) void k_gemm(
    const unsigned short* __restrict__ fbp,
    const unsigned short* __restrict__ apnl,
    unsigned short* __restrict__ xb, float* __restrict__ stpart) {
  const int nt = blockIdx.x, b = blockIdx.y;
  gemm_body(fbp, apnl, nt, b,
            [&](f32x4 (&acc)[4][4], int lane, int w) {
              gemm_epilogue(acc, lane, w, nt, xb + (size_t)b * COUT * HW2,
                            stpart + b * 64);
            });
}

// ---- PROBE: identical body; duplicate-value writes (benign), z-distinct st -
__global__ __launch_bounds__(256, 3) void k_gemmP(
    const unsigned short* __restrict__ fbp,
    const unsigned short* __restrict__ apnl,
    unsigned short* __restrict__ xb2, float* __restrict__ stp2) {
  const int nt = blockIdx.x, b = blockIdx.y, z = blockIdx.z;
  gemm_body(fbp, apnl, nt, b,
            [&](f32x4 (&acc)[4][4], int lane, int w) {
              gemm_epilogue(acc, lane, w, nt, xb2 + (size_t)b * COUT * HW2,
                            stp2 + (z * 8 + b) * 64);
            });
}

// ---- kernel 4: finalize stats ----------------------------------------------
__global__ __launch_bounds__(256) void k_fin(const float* __restrict__ stpart,
                                             float2* __restrict__ st) {
  int bg = threadIdx.x;
  float s1 = stpart[bg * 2], s2 = stpart[bg * 2 + 1];
  const float inv = 1.f / (float)GRPSZ;
  float mu = s1 * inv;
  float var = s2 * inv - mu * mu;
  st[bg] = make_float2(mu, rsqrtf(var + EPSV));
}

// ---- kernel 5: GN apply + ReLU (bf16 x -> fp32 out) ------------------------
__global__ __launch_bounds__(256) void k_apply(
    const unsigned short* __restrict__ xb, float* __restrict__ out,
    const float2* __restrict__ st, const float* __restrict__ gamma,
    const float* __restrict__ beta) {
  #pragma unroll
  for (int i = 0; i < 4; ++i) {
    unsigned e = ((unsigned)blockIdx.x * 1024 + i * 256 + threadIdx.x) * 4;
    unsigned row = (e >> 10) / 9;
    int o = row & 255;
    float2 s = st[row >> 3];
    float g = gamma[o] * s.y;
    float bb = beta[o] - s.x * g;
    ushort4 v = *(const ushort4*)(xb + e);
    float4 r;
    r.x = fmaxf(bf2f(v.x) * g + bb, 0.f);
    r.y = fmaxf(bf2f(v.y) * g + bb, 0.f);
    r.z = fmaxf(bf2f(v.z) * g + bb, 0.f);
    r.w = fmaxf(bf2f(v.w) * g + bb, 0.f);
    *(float4*)(out + e) = r;
  }
}

extern "C" void kernel_launch(void* const* d_in, const int* in_sizes, int n_in,
                              void* d_out, int out_size, void* d_ws, size_t ws_size,
                              hipStream_t stream) {
  const float* feat  = (const float*)d_in[0];
  const float* w1    = (const float*)d_in[1];
  const float* b1    = (const float*)d_in[2];
  const float* w2    = (const float*)d_in[3];
  const float* b2    = (const float*)d_in[4];
  const float* w_red = (const float*)d_in[5];
  const float* gamma = (const float*)d_in[6];
  const float* beta  = (const float*)d_in[7];
  float* out = (float*)d_out;

  char* ws = (char*)d_ws;
  unsigned short* fbp  = (unsigned short*)ws;               // 150,994,944 B
  unsigned short* apnl = (unsigned short*)(ws + 150994944); //   4,194,304 B
  unsigned short* xbb  = (unsigned short*)(ws + 155189248); //  37,748,736 B
  float* pooledpart = (float*)(ws + 192937984);             //     589,824 B
  float* pooled = (float*)(ws + 193527808);                 //      32,768 B
  float* sg     = (float*)(ws + 193560576);                 //         128 B
  float* stpart = (float*)(ws + 193560704);                 //       2,048 B
  float2* st    = (float2*)(ws + 193562752);                //       2,048 B
  // probe throwaways (never read):
  unsigned short* xb2 = (unsigned short*)(ws + 193564800);  //  37,748,736 B
  float* stp2   = (float*)(ws + 231313536);                 //       8,192 B

  // ---- real pipeline ----
  k_prep<<<dim3(18, 32, 8), 256, 0, stream>>>(feat, fbp, pooledpart);
  k_red<<<32, 256, 0, stream>>>(pooledpart, pooled);
  k_se<<<8, 256, 0, stream>>>(pooled, w1, b1, w2, b2, sg);
  k_cw<<<1024, 256, 0, stream>>>(w_red, sg, apnl, stpart);
  k_gemm<<<dim3(144, 8), 256, 0, stream>>>(fbp, apnl, xbb, stpart);
  k_fin<<<1, 256, 0, stream>>>(stpart, st);
  k_apply<<<4608, 256, 0, stream>>>(xbb, out, st, gamma, beta);
  // ---- probe: gemm x4 (z = replicas; same-value xb2 writes are benign) ----
  k_gemmP<<<dim3(144, 8, 4), 256, 0, stream>>>(fbp, apnl, xb2, stp2);
}

// Round 17
// 218.471 us; speedup vs baseline: 2.6174x; 2.6174x over previous
//
#include <hip/hip_runtime.h>
#include <hip/hip_bf16.h>

#define CIN 1024
#define HW2 9216
#define COUT 256
#define NSH 4
#define RHID 64
#define CPG 8
#define EPSV 1e-5f
#define GRPSZ (CPG * HW2)

typedef __attribute__((ext_vector_type(8))) short bf16x8;
typedef __attribute__((ext_vector_type(4))) float f32x4;

__device__ __forceinline__ unsigned short f2bf(float f) {
  unsigned u = __builtin_bit_cast(unsigned, f);
  u = (u + 0x7fffu + ((u >> 16) & 1u)) >> 16;
  return (unsigned short)u;
}
__device__ __forceinline__ float bf2f(unsigned short h) {
  unsigned u = (unsigned)h << 16;
  return __builtin_bit_cast(float, u);
}

// ---- kernel 1: feat -> bf16 panels + GAP partial sums ----------------------
__global__ __launch_bounds__(256) void k_prep(
    const float* __restrict__ feat, unsigned short* __restrict__ fbp,
    float* __restrict__ pooledpart) {
  __shared__ unsigned short T[512][36];
  const int seg = blockIdx.x, kq = blockIdx.y, b = blockIdx.z;
  const int tid = threadIdx.x, lane = tid & 63, w = tid >> 6;
  const int r = tid >> 3;
  const int c8 = tid & 7;
  const float* f0 = feat + ((size_t)(b * CIN + kq * 32 + r)) * HW2 + seg * 512;
  float s = 0.f;
  #pragma unroll
  for (int p = 0; p < 16; ++p) {
    int n0 = (c8 + p * 8) * 4;
    float4 v = *(const float4*)(f0 + n0);
    s += v.x + v.y + v.z + v.w;
    T[n0][r]     = f2bf(v.x);
    T[n0 + 1][r] = f2bf(v.y);
    T[n0 + 2][r] = f2bf(v.z);
    T[n0 + 3][r] = f2bf(v.w);
  }
  s += __shfl_down(s, 4); s += __shfl_down(s, 2); s += __shfl_down(s, 1);
  if (c8 == 0)
    pooledpart[((size_t)(b * CIN + kq * 32 + r)) * 18 + seg] = s;
  __syncthreads();
  unsigned short* dbase = fbp + ((size_t)(b * 32 + kq) * 576 + seg * 32) * 512;
  const int n16 = lane >> 2;
  const int cc = (lane & 3) ^ ((n16 & 3) ^ ((n16 >> 2) & 3));
  #pragma unroll
  for (int i = 0; i < 8; ++i) {
    int np = i * 4 + w;
    int n = np * 16 + n16;
    uint2 lo = *(const uint2*)&T[n][cc * 8];
    uint2 hi = *(const uint2*)&T[n][cc * 8 + 4];
    uint4 o = make_uint4(lo.x, lo.y, hi.x, hi.y);
    *(uint4*)(dbase + (size_t)np * 512 + lane * 8) = o;
  }
}

// ---- kernel 1b: reduce 18 seg-partials -> pooled ---------------------------
__global__ __launch_bounds__(256) void k_red(
    const float* __restrict__ pooledpart, float* __restrict__ pooled) {
  int row = blockIdx.x * 256 + threadIdx.x;
  const float* p = pooledpart + (size_t)row * 18;
  float s = 0.f;
  #pragma unroll
  for (int i = 0; i < 18; ++i) s += p[i];
  pooled[row] = s;
}

// ---- kernel 2a: SE mlp -> s[b][4] ------------------------------------------
__global__ __launch_bounds__(256) void k_se(
    const float* __restrict__ pooled, const float* __restrict__ w1,
    const float* __restrict__ b1, const float* __restrict__ w2,
    const float* __restrict__ b2, float* __restrict__ sg) {
  int b = blockIdx.x;
  int r = threadIdx.x & 63, q = threadIdx.x >> 6;
  const float* pp = pooled + b * CIN + q * 256;
  const float* wrow = w1 + (size_t)r * CIN + q * 256;
  float acc = 0.f;
  for (int c = 0; c < 256; ++c) acc += pp[c] * wrow[c];
  __shared__ float part[4][64];
  __shared__ float hid[64];
  part[q][r] = acc;
  __syncthreads();
  if (q == 0) {
    float h = (part[0][r] + part[1][r] + part[2][r] + part[3][r]) *
                  (1.f / (float)HW2) + b1[r];
    hid[r] = h > 0.f ? h : 0.f;
  }
  __syncthreads();
  if (threadIdx.x < NSH) {
    float a = 0.f;
    for (int k = 0; k < RHID; ++k) a += hid[k] * w2[threadIdx.x * RHID + k];
    a += b2[threadIdx.x];
    sg[b * NSH + threadIdx.x] = 1.f / (1.f + expf(-a));
  }
}

// ---- kernel 2b: conv_weight -> bf16; also zeroes stpart --------------------
__global__ __launch_bounds__(256) void k_cw(
    const float* __restrict__ w_red, const float* __restrict__ sg,
    unsigned short* __restrict__ cw, float* __restrict__ stpart) {
  if (blockIdx.x == 0) {
    stpart[threadIdx.x] = 0.f;
    stpart[256 + threadIdx.x] = 0.f;
  }
  int e4 = (blockIdx.x * 256 + threadIdx.x) * 4;
  int b = e4 >> 18;
  int rem = e4 & 262143;
  int i = rem & 1023;
  float sv = sg[b * NSH + (i >> 8)];
  float4 v = *(const float4*)(w_red + rem);
  ushort4 o;
  o.x = f2bf(v.x * sv); o.y = f2bf(v.y * sv);
  o.z = f2bf(v.z * sv); o.w = f2bf(v.w * sv);
  *(ushort4*)(cw + e4) = o;
}

// ---- kernel 3: batched GEMM (R13-proven body) + XCD swizzle + 4 blocks/CU --
__device__ __forceinline__ void gl16(const void* g, void* l) {
  __builtin_amdgcn_global_load_lds(
      (const __attribute__((address_space(1))) unsigned int*)g,
      (__attribute__((address_space(3))) unsigned int*)l, 16, 0, 0);
}

__global__ __launch_bounds__(256, 4) void k_gemm(
    const unsigned short* __restrict__ fbp, const unsigned short* __restrict__ cw,
    unsigned short* __restrict__ xb, float* __restrict__ stpart) {
  __shared__ unsigned short As0[128 * 32];
  __shared__ unsigned short As1[128 * 32];
  __shared__ unsigned short Bs0[128 * 32];
  __shared__ unsigned short Bs1[128 * 32];
  // XCD-locality decode: HW round-robins wgid%8 across XCDs -> b = wgid&7
  // puts each batch's 512KB A-panel set on ONE XCD's L2 (1152%8==0, bijective)
  const int wgid = blockIdx.x;
  const int b = wgid & 7;
  const int r2 = wgid >> 3;        // 0..143
  const int mt = (r2 >= 72), nt = r2 - 72 * mt;
  const int p0 = nt * 128;
  const int tid = threadIdx.x, lane = tid & 63, w = tid >> 6;
  const int wr = w >> 1, wc = w & 1;
  const unsigned short* cwb = cw + ((size_t)b * COUT + mt * 128) * CIN;
  const unsigned short* bsrc = fbp + ((size_t)(b * 32) * 576 + nt * 8) * 512 +
                               tid * 8;
  int aoff[2];
  #pragma unroll
  for (int q = 0; q < 2; ++q) {
    int c = q * 256 + tid;
    int row = c >> 2;
    aoff[q] = row * CIN + (((c & 3) ^ ((row >> 1) & 3)) * 8);
  }

  f32x4 acc[4][4] = {};

  auto STAGE = [&](unsigned short* Ad, unsigned short* Bd, int kq) {
    #pragma unroll
    for (int q = 0; q < 2; ++q)
      gl16(cwb + aoff[q] + kq * 32, &Ad[(q * 256 + w * 64) * 8]);
    #pragma unroll
    for (int q = 0; q < 2; ++q)
      gl16(bsrc + (size_t)kq * 294912 + q * 2048, &Bd[(q * 256 + w * 64) * 8]);
  };
  auto COMPUTE = [&](const unsigned short* Ac, const unsigned short* Bc) {
    bf16x8 af[4];
    #pragma unroll
    for (int mi = 0; mi < 4; ++mi) {
      int row = wr * 64 + mi * 16 + (lane & 15);
      af[mi] = *(const bf16x8*)&Ac[row * 32 +
                                   (((lane >> 4) ^ ((row >> 1) & 3)) * 8)];
    }
    bf16x8 bfv[4];
    #pragma unroll
    for (int ni = 0; ni < 4; ++ni) {
      int n = wc * 64 + ni * 16 + (lane & 15);
      int S = (n & 3) ^ ((n >> 2) & 3);
      bfv[ni] = *(const bf16x8*)&Bc[(n & 127) * 32 + (((lane >> 4) ^ S) * 8)];
    }
    #pragma unroll
    for (int mi = 0; mi < 4; ++mi)
      #pragma unroll
      for (int ni = 0; ni < 4; ++ni)
        acc[mi][ni] = __builtin_amdgcn_mfma_f32_16x16x32_bf16(
            af[mi], bfv[ni], acc[mi][ni], 0, 0, 0);
  };

  STAGE(As0, Bs0, 0);
  __syncthreads();
  for (int kk = 0; kk < 15; ++kk) {
    STAGE(As1, Bs1, 2 * kk + 1);
    COMPUTE(As0, Bs0);
    __syncthreads();
    STAGE(As0, Bs0, 2 * kk + 2);
    COMPUTE(As1, Bs1);
    __syncthreads();
  }
  STAGE(As1, Bs1, 31);
  COMPUTE(As0, Bs0);
  __syncthreads();
  COMPUTE(As1, Bs1);

  unsigned short* ob = xb + (size_t)b * COUT * HW2;
  #pragma unroll
  for (int mi = 0; mi < 4; ++mi) {
    int r0 = mt * 128 + wr * 64 + mi * 16 + ((lane >> 4) << 2);
    #pragma unroll
    for (int ni = 0; ni < 4; ++ni) {
      int p = p0 + wc * 64 + ni * 16 + (lane & 15);
      #pragma unroll
      for (int j = 0; j < 4; ++j)
        ob[(size_t)(r0 + j) * HW2 + p] = f2bf(acc[mi][ni][j]);
    }
  }

  #pragma unroll
  for (int mi = 0; mi < 4; ++mi) {
    float s1 = 0.f, s2 = 0.f;
    #pragma unroll
    for (int ni = 0; ni < 4; ++ni)
      #pragma unroll
      for (int j = 0; j < 4; ++j) {
        float v = acc[mi][ni][j];
        s1 += v; s2 += v * v;
      }
    #pragma unroll
    for (int off = 1; off <= 16; off <<= 1) {
      s1 += __shfl_xor(s1, off);
      s2 += __shfl_xor(s2, off);
    }
    if ((lane & 31) == 0) {
      int g = mt * 16 + wr * 8 + mi * 2 + (lane >> 5);
      atomicAdd(&stpart[(b * 32 + g) * 2], s1);
      atomicAdd(&stpart[(b * 32 + g) * 2 + 1], s2);
    }
  }
}

// ---- kernel 4: finalize stats ----------------------------------------------
__global__ __launch_bounds__(256) void k_fin(const float* __restrict__ stpart,
                                             float2* __restrict__ st) {
  int bg = threadIdx.x;
  float s1 = stpart[bg * 2], s2 = stpart[bg * 2 + 1];
  const float inv = 1.f / (float)GRPSZ;
  float mu = s1 * inv;
  float var = s2 * inv - mu * mu;
  st[bg] = make_float2(mu, rsqrtf(var + EPSV));
}

// ---- kernel 5: GN apply + ReLU (bf16 x -> fp32 out) ------------------------
__global__ __launch_bounds__(256) void k_apply(
    const unsigned short* __restrict__ xb, float* __restrict__ out,
    const float2* __restrict__ st, const float* __restrict__ gamma,
    const float* __restrict__ beta) {
  #pragma unroll
  for (int i = 0; i < 4; ++i) {
    unsigned e = ((unsigned)blockIdx.x * 1024 + i * 256 + threadIdx.x) * 4;
    unsigned row = (e >> 10) / 9;
    int o = row & 255;
    float2 s = st[row >> 3];
    float g = gamma[o] * s.y;
    float bb = beta[o] - s.x * g;
    ushort4 v = *(const ushort4*)(xb + e);
    float4 r;
    r.x = fmaxf(bf2f(v.x) * g + bb, 0.f);
    r.y = fmaxf(bf2f(v.y) * g + bb, 0.f);
    r.z = fmaxf(bf2f(v.z) * g + bb, 0.f);
    r.w = fmaxf(bf2f(v.w) * g + bb, 0.f);
    *(float4*)(out + e) = r;
  }
}

extern "C" void kernel_launch(void* const* d_in, const int* in_sizes, int n_in,
                              void* d_out, int out_size, void* d_ws, size_t ws_size,
                              hipStream_t stream) {
  const float* feat  = (const float*)d_in[0];
  const float* w1    = (const float*)d_in[1];
  const float* b1    = (const float*)d_in[2];
  const float* w2    = (const float*)d_in[3];
  const float* b2    = (const float*)d_in[4];
  const float* w_red = (const float*)d_in[5];
  const float* gamma = (const float*)d_in[6];
  const float* beta  = (const float*)d_in[7];
  float* out = (float*)d_out;

  char* ws = (char*)d_ws;
  unsigned short* fbp = (unsigned short*)ws;                // 150,994,944 B
  unsigned short* cw  = (unsigned short*)(ws + 150994944);  //   4,194,304 B
  unsigned short* xbb = (unsigned short*)(ws + 155189248);  //  37,748,736 B
  float* pooledpart = (float*)(ws + 192937984);             //     589,824 B
  float* pooled = (float*)(ws + 193527808);                 //      32,768 B
  float* sg     = (float*)(ws + 193560576);                 //         128 B
  float* stpart = (float*)(ws + 193560704);                 //       2,048 B
  float2* st    = (float2*)(ws + 193562752);                //       2,048 B

  k_prep<<<dim3(18, 32, 8), 256, 0, stream>>>(feat, fbp, pooledpart);
  k_red<<<32, 256, 0, stream>>>(pooledpart, pooled);
  k_se<<<8, 256, 0, stream>>>(pooled, w1, b1, w2, b2, sg);
  k_cw<<<2048, 256, 0, stream>>>(w_red, sg, cw, stpart);
  k_gemm<<<1152, 256, 0, stream>>>(fbp, cw, xbb, stpart);
  k_fin<<<1, 256, 0, stream>>>(stpart, st);
  k_apply<<<4608, 256, 0, stream>>>(xbb, out, st, gamma, beta);
}